// Round 9
// baseline (211.359 us; speedup 1.0000x reference)
//
#include <hip/hip_runtime.h>
#include <math.h>

// Problem constants (fixed by the reference)
namespace {
constexpr int IN_DIMc = 159;   // L1*(DIM+1)+L2
constexpr int MDIMc   = 93;    // L2*DIM
constexpr int MATELc  = 2976;  // banded tril nnz
constexpr int ROWS    = MDIMc + MATELc;  // 3069
constexpr int SIGDIMc = 340;   // 4+16+64+256
constexpr int NCLSc   = 10;
}

// Device-global scratch (static: no ws_size assumption; fully rewritten
// every launch).
__device__ float g_mc[256 * 3072];    // [B][3069] mean|cov (rows 3069..3071 unused)
__device__ float g_psig[512 * 340];   // per-half-batch partial signature sums

// --------------------------------------------------------------------------
// Kernel 1: g_mc[b][r] = dot(x[b,:159], Wcat[r,:159]) + bcat[r]
// Tile: 64 rows x 32 batches per 256-thread block. W tile in LDS (b128
// per-lane reads, stride 164); x read via wave-uniform global loads.
// --------------------------------------------------------------------------
__global__ __launch_bounds__(256) void gemm_mc(
    const float* __restrict__ x, const float* __restrict__ Wm,
    const float* __restrict__ bm, const float* __restrict__ Wc,
    const float* __restrict__ bc)
{
  __shared__ __align__(16) float wls[64 * 164];  // [row][164], cols 159..163 = 0
  const int t  = threadIdx.x;
  const int r0 = blockIdx.x * 64;
  const int b0 = blockIdx.y * 32;

  for (int idx = t; idx < 64 * 164; idx += 256) {
    int rr = idx / 164, ii = idx - rr * 164;
    int r = r0 + rr;
    float v = 0.0f;
    if (ii < IN_DIMc) {
      if (r < MDIMc)      v = Wm[r * IN_DIMc + ii];
      else if (r < ROWS)  v = Wc[(r - MDIMc) * IN_DIMc + ii];
    }
    wls[idx] = v;
  }
  __syncthreads();

  const int rl = t & 63;    // row within tile
  const int bg = t >> 6;    // wave index = batch group (8 batches)
  const float* xr[8];
#pragma unroll
  for (int j = 0; j < 8; ++j) xr[j] = x + (b0 + bg * 8 + j) * IN_DIMc;

  float acc[8] = {0, 0, 0, 0, 0, 0, 0, 0};
  const float4* wls4 = (const float4*)wls;
  for (int c = 0; c < 39; ++c) {          // i = 0..155
    float4 wv = wls4[rl * 41 + c];
    const int i = c * 4;
#pragma unroll
    for (int j = 0; j < 8; ++j) {
      acc[j] = fmaf(wv.x, xr[j][i],     acc[j]);
      acc[j] = fmaf(wv.y, xr[j][i + 1], acc[j]);
      acc[j] = fmaf(wv.z, xr[j][i + 2], acc[j]);
      acc[j] = fmaf(wv.w, xr[j][i + 3], acc[j]);
    }
  }
  for (int i = 156; i < IN_DIMc; ++i) {   // epilogue (no x OOB read)
    float wv = wls[rl * 164 + i];
#pragma unroll
    for (int j = 0; j < 8; ++j) acc[j] = fmaf(wv, xr[j][i], acc[j]);
  }

  const int r = r0 + rl;
  if (r < ROWS) {
    float bias = (r < MDIMc) ? bm[r] : bc[r - MDIMc];
#pragma unroll
    for (int j = 0; j < 8; ++j)
      g_mc[(size_t)(b0 + bg * 8 + j) * ROWS + r] = acc[j] + bias;
  }
}

// --------------------------------------------------------------------------
// Kernel 2: 512 blocks (2 per batch), 1024 threads = 16 waves, 2 paths/wave.
// Block bx handles batch b = bx>>1, paths [h*32, h*32+32) with h = bx&1.
// 51.5 KB LDS -> 2 blocks/CU -> 32 waves/CU (8/SIMD).
//  P0: stage x, mean, and the block's 32 eps columns.
//  P1: newV[93][32] = banded-tril(cov) @ eps + mean (cov via global loads).
//  P2: barrier-free per-wave Chen recursion, FULLY UNROLLED 62-step loop
//      (static LDS offsets -> no float4 rotation movs, no loop overhead);
//      shuffle norm-reduce; lambda: 25-iter fully-unrolled bisection
//      (interval 2^-25 ~ 3e-8 << 5e-2 threshold; norm2<=4 -> lam=1).
//  P3: reduce 16 waves -> 340 partial sums -> g_psig[bx].
// Lane layout: l = a*16+b*4+c. Lane holds S4[4l..4l+3], S3[l],
// S2[l>>2] (x4 replicated), S1[l>>4] (x16 replicated).
// --------------------------------------------------------------------------
__global__ __launch_bounds__(1024, 8) void path_sig(
    const float* __restrict__ x, const float* __restrict__ eps)
{
  // LDS (floats). eps region [0,2976) dead after P1 -> aliased by part[5440].
  // Total 12864 floats = 51,456 B; 2 blocks = 102.9 KB < 160 KB/CU.
  constexpr int OFF_EPS  = 0;      // 2976  [93][32]
  constexpr int OFF_PART = 0;      // alias: 16 * 340 = 5440
  constexpr int OFF_MEAN = 5440;   // 93 (+3 pad)
  constexpr int OFF_XS   = 5536;   // 159 (+1 pad)
  constexpr int OFF_NEWV = 5696;   // 93*33 = 3069 -> ends 8765 (+3 pad)
  constexpr int OFF_DX   = 8768;   // 16 waves * 64 float4 = 4096 -> ends 12864
  __shared__ __align__(16) float smem[12864];
  float* epsL  = smem + OFF_EPS;
  float* meanL = smem + OFF_MEAN;
  float* xsm   = smem + OFF_XS;
  float* newVL = smem + OFF_NEWV;

  const int t  = threadIdx.x;
  const int bx = blockIdx.x;
  const int b  = bx >> 1;
  const int h  = bx & 1;

  // ---- P0: stage inputs ----
  if (t < IN_DIMc) xsm[t] = x[b * IN_DIMc + t];
  else if (t >= 512 && t < 512 + MDIMc)
    meanL[t - 512] = g_mc[(size_t)b * ROWS + (t - 512)];
  {
    // this block's 32 eps columns: 93 rows x 8 float4
    const float4* ep4 = (const float4*)eps;
    float4* el4 = (float4*)epsL;
    if (t < 93 * 8) {
      int r = t >> 3, c4 = t & 7;
      el4[r * 8 + c4] = ep4[((size_t)b * 93 + r) * 16 + h * 8 + c4];
    }
  }
  __syncthreads();

  // ---- P1: newV[r][col] for the block's 32 columns ----
  const int l = t & 63;
  const int w = t >> 6;           // wave id 0..15
  {
    const int col = l & 31;
    const int h2  = l >> 5;
    const float* covG = g_mc + (size_t)b * ROWS + MDIMc;
    for (int r = (w << 1) | h2; r < MDIMc; r += 32) {
      const int X  = r / 3;
      const int tr = r - X * 3;
      float acc = meanL[r];
      const int tb = (tr * (tr + 1)) >> 1;
      for (int y = 0; y <= X; ++y) {
        const int i = X - y;                              // diagonal offset
        const int base = 6 * (31 * i - ((i * (i - 1)) >> 1)) + y * 6 + tb;
        for (int tc2 = 0; tc2 <= tr; ++tc2)
          acc = fmaf(covG[base + tc2], epsL[(y * 3 + tc2) * 32 + col], acc);
      }
      newVL[r * 33 + col] = acc;
    }
  }
  __syncthreads();   // newV/xsm stable; no more barriers until P3

  // ---- P2: signatures (barrier-free; dx is wave-private LDS) ----
  const int la = l >> 4, lb = (l >> 2) & 3, lc = l & 3;
  const bool aH = (la & 2) != 0, aL = (la & 1) != 0;
  const bool bH = (lb & 2) != 0, bL = (lb & 1) != 0;
  const bool cH = (lc & 2) != 0, cL = (lc & 1) != 0;
  float* dxb = smem + OFF_DX + w * 256;     // 62 float4 slots used
  float acc1 = 0.f, acc2 = 0.f, acc3 = 0.f;
  float4 acc4 = make_float4(0.f, 0.f, 0.f, 0.f);
  const float inv6 = 1.0f / 6.0f, inv24 = 1.0f / 24.0f;

#pragma unroll 1
  for (int j = 0; j < 2; ++j) {
    const int kk2 = (w << 1) | j;           // path-in-block 0..31
    // increment buffer dx[i] = p[i+1]-p[i]; even i: old->new, odd: new->old
    if (l < 62) {
      const int m = l >> 1;
      float4 dv;
      if ((l & 1) == 0) {
        dv.x = newVL[(3 * m) * 33 + kk2]     - xsm[3 * m];
        dv.y = newVL[(3 * m + 1) * 33 + kk2] - xsm[3 * m + 1];
        dv.z = newVL[(3 * m + 2) * 33 + kk2] - xsm[3 * m + 2];
        dv.w = xsm[128 + m] - xsm[96 + m];
      } else {
        dv.x = xsm[3 * m + 3] - newVL[(3 * m) * 33 + kk2];
        dv.y = xsm[3 * m + 4] - newVL[(3 * m + 1) * 33 + kk2];
        dv.z = xsm[3 * m + 5] - newVL[(3 * m + 2) * 33 + kk2];
        dv.w = xsm[96 + m + 1] - xsm[128 + m];
      }
      *(float4*)(dxb + l * 4) = dv;
    }
    // no __syncthreads: dxb is wave-private (same-wave lgkmcnt ordering)

    float s1a = 0.f, s2o = 0.f, s3 = 0.f;
    float4 s4 = make_float4(0.f, 0.f, 0.f, 0.f);
    const float4* dx4 = (const float4*)dxb;
#pragma unroll
    for (int i = 0; i < 62; ++i) {     // FULL unroll: static ds offsets,
      float4 d = dx4[i];               // no rotation movs, no loop overhead
      float dxa  = aH ? (aL ? d.w : d.z) : (aL ? d.y : d.x);
      float dxbv = bH ? (bL ? d.w : d.z) : (bL ? d.y : d.x);
      float dxc  = cH ? (cL ? d.w : d.z) : (cL ? d.y : d.x);
      float bcv = dxbv * dxc;
      float i1 = fmaf(s1a, inv6, dxa * inv24);  // S1/6 + dxa/24
      float i2 = fmaf(s1a, 0.5f, dxa * inv6);   // S1/2 + dxa/6
      float u  = s2o * dxc;
      float cB = fmaf(u, 0.5f, s3);
      // T4[abcd] = S4 + dxd*(dxa*bc/24 + S1[a]*bc/6 + S2[ab]*dxc/2 + S3[abc])
      float coef = fmaf(i1, bcv, cB);
      s4.x = fmaf(coef, d.x, s4.x);
      s4.y = fmaf(coef, d.y, s4.y);
      s4.z = fmaf(coef, d.z, s4.z);
      s4.w = fmaf(coef, d.w, s4.w);
      // T3[abc] = S3 + dxa*bc/6 + S1[a]*bc/2 + S2[ab]*dxc
      s3 = fmaf(i2, bcv, u + s3);
      // T2[ab] = S2 + dxb*(dxa/2 + S1[a])
      s2o = fmaf(dxbv, fmaf(dxa, 0.5f, s1a), s2o);
      // T1[a] = S1 + dxa
      s1a += dxa;
    }

    // ---- tensor normalization (Chevyrev-Oberhauser) ----
    float c4 = s4.x * s4.x + s4.y * s4.y + s4.z * s4.z + s4.w * s4.w;
    float c3v = s3 * s3;
    float c2v = (lc == 0) ? s2o * s2o : 0.f;          // count each S2 once
    float c1v = ((l & 15) == 0) ? s1a * s1a : 0.f;    // count each S1 once
#pragma unroll
    for (int off = 1; off < 64; off <<= 1) {
      c1v += __shfl_xor(c1v, off);
      c2v += __shfl_xor(c2v, off);
      c3v += __shfl_xor(c3v, off);
      c4  += __shfl_xor(c4, off);
    }
    float norm2 = 1.f + c1v + c2v + c3v + c4;
    float lam, lam2;
    if (norm2 <= 4.0f) {          // wave-uniform: phi(x)=x -> lam -> 1
      lam = 1.0f; lam2 = 1.0f;
    } else {
      // bisection on the quartic in m2 = lam^2. 25 iters -> interval 2^-25
      // (~3e-8), vs reference's 40; sig delta ~1e-7 << 5e-2 threshold.
      float psi = 8.0f - 16.0f / norm2;
      float lo = 0.f, hi = 1.f;
#pragma unroll
      for (int it = 0; it < 25; ++it) {
        float mid = 0.5f * (lo + hi);
        float m2 = mid * mid;
        float val =
            fmaf(m2, fmaf(m2, fmaf(m2, fmaf(m2, c4, c3v), c2v), c1v), 1.f);
        bool pos = val > psi;
        hi = pos ? mid : hi;
        lo = pos ? lo : mid;
      }
      lam = 0.5f * (lo + hi);
      lam2 = lam * lam;
    }
    const float lam3 = lam2 * lam, lam4 = lam2 * lam2;
    acc1 = fmaf(s1a, lam, acc1);
    acc2 = fmaf(s2o, lam2, acc2);
    acc3 = fmaf(s3, lam3, acc3);
    acc4.x = fmaf(s4.x, lam4, acc4.x);
    acc4.y = fmaf(s4.y, lam4, acc4.y);
    acc4.z = fmaf(s4.z, lam4, acc4.z);
    acc4.w = fmaf(s4.w, lam4, acc4.w);
  }

  // ---- P3: reduce over waves -> partial sums to global ----
  {
    float* part = smem + OFF_PART + w * SIGDIMc;   // aliases dead eps region
    if ((l & 15) == 0) part[l >> 4] = acc1;        // S1[0..3]
    if (lc == 0)       part[4 + (l >> 2)] = acc2;  // S2[0..15]
    part[20 + l] = acc3;                           // S3[0..63]
    *(float4*)(part + 84 + 4 * l) = acc4;          // S4[0..255]
  }
  __syncthreads();

  if (t < SIGDIMc) {
    float s = 0.f;
#pragma unroll
    for (int ww = 0; ww < 16; ++ww) s += smem[OFF_PART + ww * SIGDIMc + t];
    g_psig[(size_t)bx * SIGDIMc + t] = s;
  }
}

// --------------------------------------------------------------------------
// Kernel 3: merge the two half-batch partials, /64, 340x10 linear,
// log_softmax. One wave per batch; everything in registers.
// --------------------------------------------------------------------------
__global__ __launch_bounds__(64) void finish(
    const float* __restrict__ Wf, const float* __restrict__ bf,
    float* __restrict__ out)
{
  const int b = blockIdx.x;
  const int l = threadIdx.x;
  float sigv[6];
#pragma unroll
  for (int ii = 0; ii < 6; ++ii) {
    int jj = l + ii * 64;
    sigv[ii] = (jj < SIGDIMc)
        ? (g_psig[(size_t)(2 * b) * SIGDIMc + jj] +
           g_psig[(size_t)(2 * b + 1) * SIGDIMc + jj]) * (1.0f / 64.0f)
        : 0.f;
  }
  float lgv[NCLSc];
#pragma unroll 1
  for (int c = 0; c < NCLSc; ++c) {
    float s = 0.f;
#pragma unroll
    for (int ii = 0; ii < 6; ++ii) {
      int jj = l + ii * 64;
      if (jj < SIGDIMc) s = fmaf(sigv[ii], Wf[c * SIGDIMc + jj], s);
    }
#pragma unroll
    for (int off = 1; off < 64; off <<= 1) s += __shfl_xor(s, off);
    lgv[c] = s + bf[c];
  }
  if (l < NCLSc) {
    float mx = lgv[0];
#pragma unroll
    for (int i2 = 1; i2 < NCLSc; ++i2) mx = fmaxf(mx, lgv[i2]);
    float se = 0.f;
#pragma unroll
    for (int i2 = 0; i2 < NCLSc; ++i2) se += expf(lgv[i2] - mx);
    out[b * NCLSc + l] = lgv[l] - mx - logf(se);
  }
}

extern "C" void kernel_launch(void* const* d_in, const int* in_sizes, int n_in,
                              void* d_out, int out_size, void* d_ws, size_t ws_size,
                              hipStream_t stream) {
  (void)in_sizes; (void)n_in; (void)out_size; (void)d_ws; (void)ws_size;
  const float* x   = (const float*)d_in[0];
  const float* Wm  = (const float*)d_in[1];
  const float* bm  = (const float*)d_in[2];
  const float* Wc  = (const float*)d_in[3];
  const float* bcv = (const float*)d_in[4];
  const float* Wf  = (const float*)d_in[5];
  const float* bf  = (const float*)d_in[6];
  const float* eps = (const float*)d_in[7];
  // d_in[8]/d_in[9] (x_idx/y_idx) are compile-time deterministic; hard-coded.
  float* out = (float*)d_out;

  gemm_mc<<<dim3(48, 8), 256, 0, stream>>>(x, Wm, bm, Wc, bcv);
  path_sig<<<dim3(512), 1024, 0, stream>>>(x, eps);
  finish<<<dim3(256), 64, 0, stream>>>(Wf, bf, out);
}

// Round 10
// 196.442 us; speedup vs baseline: 1.0759x; 1.0759x over previous
//
#include <hip/hip_runtime.h>
#include <math.h>

// Problem constants (fixed by the reference)
namespace {
constexpr int IN_DIMc = 159;   // L1*(DIM+1)+L2
constexpr int MDIMc   = 93;    // L2*DIM
constexpr int MATELc  = 2976;  // banded tril nnz
constexpr int ROWS    = MDIMc + MATELc;  // 3069
constexpr int SIGDIMc = 340;   // 4+16+64+256
constexpr int NCLSc   = 10;
}

// Device-global scratch (static: no ws_size assumption; fully rewritten
// every launch).
__device__ float g_mc[256 * 3072];    // [B][3069] mean|cov (rows 3069..3071 unused)
__device__ float g_psig[512 * 340];   // per-half-batch partial signature sums

// --------------------------------------------------------------------------
// Kernel 1: g_mc[b][r] = dot(x[b,:159], Wcat[r,:159]) + bcat[r]
// Tile: 64 rows x 32 batches per 256-thread block. W tile in LDS (b128
// per-lane reads, stride 164); x read via wave-uniform global loads.
// --------------------------------------------------------------------------
__global__ __launch_bounds__(256) void gemm_mc(
    const float* __restrict__ x, const float* __restrict__ Wm,
    const float* __restrict__ bm, const float* __restrict__ Wc,
    const float* __restrict__ bc)
{
  __shared__ __align__(16) float wls[64 * 164];  // [row][164], cols 159..163 = 0
  const int t  = threadIdx.x;
  const int r0 = blockIdx.x * 64;
  const int b0 = blockIdx.y * 32;

  for (int idx = t; idx < 64 * 164; idx += 256) {
    int rr = idx / 164, ii = idx - rr * 164;
    int r = r0 + rr;
    float v = 0.0f;
    if (ii < IN_DIMc) {
      if (r < MDIMc)      v = Wm[r * IN_DIMc + ii];
      else if (r < ROWS)  v = Wc[(r - MDIMc) * IN_DIMc + ii];
    }
    wls[idx] = v;
  }
  __syncthreads();

  const int rl = t & 63;    // row within tile
  const int bg = t >> 6;    // wave index = batch group (8 batches)
  const float* xr[8];
#pragma unroll
  for (int j = 0; j < 8; ++j) xr[j] = x + (b0 + bg * 8 + j) * IN_DIMc;

  float acc[8] = {0, 0, 0, 0, 0, 0, 0, 0};
  const float4* wls4 = (const float4*)wls;
  for (int c = 0; c < 39; ++c) {          // i = 0..155
    float4 wv = wls4[rl * 41 + c];
    const int i = c * 4;
#pragma unroll
    for (int j = 0; j < 8; ++j) {
      acc[j] = fmaf(wv.x, xr[j][i],     acc[j]);
      acc[j] = fmaf(wv.y, xr[j][i + 1], acc[j]);
      acc[j] = fmaf(wv.z, xr[j][i + 2], acc[j]);
      acc[j] = fmaf(wv.w, xr[j][i + 3], acc[j]);
    }
  }
  for (int i = 156; i < IN_DIMc; ++i) {   // epilogue (no x OOB read)
    float wv = wls[rl * 164 + i];
#pragma unroll
    for (int j = 0; j < 8; ++j) acc[j] = fmaf(wv, xr[j][i], acc[j]);
  }

  const int r = r0 + rl;
  if (r < ROWS) {
    float bias = (r < MDIMc) ? bm[r] : bc[r - MDIMc];
#pragma unroll
    for (int j = 0; j < 8; ++j)
      g_mc[(size_t)(b0 + bg * 8 + j) * ROWS + r] = acc[j] + bias;
  }
}

// --------------------------------------------------------------------------
// Kernel 2: 512 blocks (2 per batch), 1024 threads = 16 waves, 2 paths/wave.
// Block bx handles batch b = bx>>1, paths [h*32, h*32+32) with h = bx&1.
// 51.5 KB LDS -> 2 blocks/CU -> 32 waves/CU (8/SIMD, CU wave capacity).
//  P0: stage x, mean, and the block's 32 eps columns.
//  P1: newV[93][32] = banded-tril(cov) @ eps + mean (cov via global loads).
//  P2: barrier-free per-wave Chen recursion, unroll-2 loop (R9 full unroll
//      caused VGPR spill: WRITE_SIZE 0.7->27 MB). Per step: 1 broadcast
//      ds_read_b128 for d + 3 per-lane-offset ds_read_b32 for dxa/dxb/dxc
//      (4 distinct addrs -> 4 banks + broadcast: conflict-free) - replaces
//      9 cndmask selects (VALU was the bottleneck pipe at 88% busy).
//      Norm shuffle-reduce; lambda: 25-iter unrolled bisection (interval
//      2^-25 ~ 3e-8 << 5e-2 threshold; R9 verified absmax 0.0).
//  P3: reduce 16 waves -> 340 partial sums -> g_psig[bx].
// Lane layout: l = a*16+b*4+c. Lane holds S4[4l..4l+3], S3[l],
// S2[l>>2] (x4 replicated), S1[l>>4] (x16 replicated).
// --------------------------------------------------------------------------
__global__ __launch_bounds__(1024, 8) void path_sig(
    const float* __restrict__ x, const float* __restrict__ eps)
{
  // LDS (floats). eps region [0,2976) dead after P1 -> aliased by part[5440].
  // Total 12864 floats = 51,456 B; 2 blocks = 102.9 KB < 160 KB/CU.
  constexpr int OFF_EPS  = 0;      // 2976  [93][32]
  constexpr int OFF_PART = 0;      // alias: 16 * 340 = 5440
  constexpr int OFF_MEAN = 5440;   // 93 (+3 pad)
  constexpr int OFF_XS   = 5536;   // 159 (+1 pad)
  constexpr int OFF_NEWV = 5696;   // 93*33 = 3069 -> ends 8765 (+3 pad)
  constexpr int OFF_DX   = 8768;   // 16 waves * 64 float4 = 4096 -> ends 12864
  __shared__ __align__(16) float smem[12864];
  float* epsL  = smem + OFF_EPS;
  float* meanL = smem + OFF_MEAN;
  float* xsm   = smem + OFF_XS;
  float* newVL = smem + OFF_NEWV;

  const int t  = threadIdx.x;
  const int bx = blockIdx.x;
  const int b  = bx >> 1;
  const int h  = bx & 1;

  // ---- P0: stage inputs ----
  if (t < IN_DIMc) xsm[t] = x[b * IN_DIMc + t];
  else if (t >= 512 && t < 512 + MDIMc)
    meanL[t - 512] = g_mc[(size_t)b * ROWS + (t - 512)];
  {
    // this block's 32 eps columns: 93 rows x 8 float4
    const float4* ep4 = (const float4*)eps;
    float4* el4 = (float4*)epsL;
    if (t < 93 * 8) {
      int r = t >> 3, c4 = t & 7;
      el4[r * 8 + c4] = ep4[((size_t)b * 93 + r) * 16 + h * 8 + c4];
    }
  }
  __syncthreads();

  // ---- P1: newV[r][col] for the block's 32 columns ----
  const int l = t & 63;
  const int w = t >> 6;           // wave id 0..15
  {
    const int col = l & 31;
    const int h2  = l >> 5;
    const float* covG = g_mc + (size_t)b * ROWS + MDIMc;
    for (int r = (w << 1) | h2; r < MDIMc; r += 32) {
      const int X  = r / 3;
      const int tr = r - X * 3;
      float acc = meanL[r];
      const int tb = (tr * (tr + 1)) >> 1;
      for (int y = 0; y <= X; ++y) {
        const int i = X - y;                              // diagonal offset
        const int base = 6 * (31 * i - ((i * (i - 1)) >> 1)) + y * 6 + tb;
        for (int tc2 = 0; tc2 <= tr; ++tc2)
          acc = fmaf(covG[base + tc2], epsL[(y * 3 + tc2) * 32 + col], acc);
      }
      newVL[r * 33 + col] = acc;
    }
  }
  __syncthreads();   // newV/xsm stable; no more barriers until P3

  // ---- P2: signatures (barrier-free; dx is wave-private LDS) ----
  const int la = l >> 4, lb = (l >> 2) & 3, lc = l & 3;
  float* dxb = smem + OFF_DX + w * 256;     // 62 float4 slots used
  float acc1 = 0.f, acc2 = 0.f, acc3 = 0.f;
  float4 acc4 = make_float4(0.f, 0.f, 0.f, 0.f);
  const float inv6 = 1.0f / 6.0f, inv24 = 1.0f / 24.0f;

#pragma unroll 1
  for (int j = 0; j < 2; ++j) {
    const int kk2 = (w << 1) | j;           // path-in-block 0..31
    // increment buffer dx[i] = p[i+1]-p[i]; even i: old->new, odd: new->old
    if (l < 62) {
      const int m = l >> 1;
      float4 dv;
      if ((l & 1) == 0) {
        dv.x = newVL[(3 * m) * 33 + kk2]     - xsm[3 * m];
        dv.y = newVL[(3 * m + 1) * 33 + kk2] - xsm[3 * m + 1];
        dv.z = newVL[(3 * m + 2) * 33 + kk2] - xsm[3 * m + 2];
        dv.w = xsm[128 + m] - xsm[96 + m];
      } else {
        dv.x = xsm[3 * m + 3] - newVL[(3 * m) * 33 + kk2];
        dv.y = xsm[3 * m + 4] - newVL[(3 * m + 1) * 33 + kk2];
        dv.z = xsm[3 * m + 5] - newVL[(3 * m + 2) * 33 + kk2];
        dv.w = xsm[96 + m + 1] - xsm[128 + m];
      }
      *(float4*)(dxb + l * 4) = dv;
    }
    // no __syncthreads: dxb is wave-private (same-wave lgkmcnt ordering)

    float s1a = 0.f, s2o = 0.f, s3 = 0.f;
    float4 s4 = make_float4(0.f, 0.f, 0.f, 0.f);
    const float4* dx4 = (const float4*)dxb;
#pragma unroll 2
    for (int i = 0; i < 62; ++i) {
      float4 d = dx4[i];                  // broadcast b128
      float dxa  = dxb[i * 4 + la];       // per-lane-offset b32 (bank-clean)
      float dxbv = dxb[i * 4 + lb];
      float dxc  = dxb[i * 4 + lc];
      float bcv = dxbv * dxc;
      float i1 = fmaf(s1a, inv6, dxa * inv24);  // S1/6 + dxa/24
      float i2 = fmaf(s1a, 0.5f, dxa * inv6);   // S1/2 + dxa/6
      float u  = s2o * dxc;
      float cB = fmaf(u, 0.5f, s3);
      // T4[abcd] = S4 + dxd*(dxa*bc/24 + S1[a]*bc/6 + S2[ab]*dxc/2 + S3[abc])
      float coef = fmaf(i1, bcv, cB);
      s4.x = fmaf(coef, d.x, s4.x);
      s4.y = fmaf(coef, d.y, s4.y);
      s4.z = fmaf(coef, d.z, s4.z);
      s4.w = fmaf(coef, d.w, s4.w);
      // T3[abc] = S3 + dxa*bc/6 + S1[a]*bc/2 + S2[ab]*dxc
      s3 = fmaf(i2, bcv, u + s3);
      // T2[ab] = S2 + dxb*(dxa/2 + S1[a])
      s2o = fmaf(dxbv, fmaf(dxa, 0.5f, s1a), s2o);
      // T1[a] = S1 + dxa
      s1a += dxa;
    }

    // ---- tensor normalization (Chevyrev-Oberhauser) ----
    float c4 = s4.x * s4.x + s4.y * s4.y + s4.z * s4.z + s4.w * s4.w;
    float c3v = s3 * s3;
    float c2v = (lc == 0) ? s2o * s2o : 0.f;          // count each S2 once
    float c1v = ((l & 15) == 0) ? s1a * s1a : 0.f;    // count each S1 once
#pragma unroll
    for (int off = 1; off < 64; off <<= 1) {
      c1v += __shfl_xor(c1v, off);
      c2v += __shfl_xor(c2v, off);
      c3v += __shfl_xor(c3v, off);
      c4  += __shfl_xor(c4, off);
    }
    float norm2 = 1.f + c1v + c2v + c3v + c4;
    float lam, lam2;
    if (norm2 <= 4.0f) {          // wave-uniform: phi(x)=x -> lam -> 1
      lam = 1.0f; lam2 = 1.0f;
    } else {
      // bisection on the quartic in m2 = lam^2. 25 iters -> interval 2^-25
      // (~3e-8), vs reference's 40; sig delta ~1e-7 << 5e-2 threshold.
      float psi = 8.0f - 16.0f / norm2;
      float lo = 0.f, hi = 1.f;
#pragma unroll
      for (int it = 0; it < 25; ++it) {
        float mid = 0.5f * (lo + hi);
        float m2 = mid * mid;
        float val =
            fmaf(m2, fmaf(m2, fmaf(m2, fmaf(m2, c4, c3v), c2v), c1v), 1.f);
        bool pos = val > psi;
        hi = pos ? mid : hi;
        lo = pos ? lo : mid;
      }
      lam = 0.5f * (lo + hi);
      lam2 = lam * lam;
    }
    const float lam3 = lam2 * lam, lam4 = lam2 * lam2;
    acc1 = fmaf(s1a, lam, acc1);
    acc2 = fmaf(s2o, lam2, acc2);
    acc3 = fmaf(s3, lam3, acc3);
    acc4.x = fmaf(s4.x, lam4, acc4.x);
    acc4.y = fmaf(s4.y, lam4, acc4.y);
    acc4.z = fmaf(s4.z, lam4, acc4.z);
    acc4.w = fmaf(s4.w, lam4, acc4.w);
  }

  // ---- P3: reduce over waves -> partial sums to global ----
  {
    float* part = smem + OFF_PART + w * SIGDIMc;   // aliases dead eps region
    if ((l & 15) == 0) part[l >> 4] = acc1;        // S1[0..3]
    if (lc == 0)       part[4 + (l >> 2)] = acc2;  // S2[0..15]
    part[20 + l] = acc3;                           // S3[0..63]
    *(float4*)(part + 84 + 4 * l) = acc4;          // S4[0..255]
  }
  __syncthreads();

  if (t < SIGDIMc) {
    float s = 0.f;
#pragma unroll
    for (int ww = 0; ww < 16; ++ww) s += smem[OFF_PART + ww * SIGDIMc + t];
    g_psig[(size_t)bx * SIGDIMc + t] = s;
  }
}

// --------------------------------------------------------------------------
// Kernel 3: merge the two half-batch partials, /64, 340x10 linear,
// log_softmax. One wave per batch; everything in registers.
// --------------------------------------------------------------------------
__global__ __launch_bounds__(64) void finish(
    const float* __restrict__ Wf, const float* __restrict__ bf,
    float* __restrict__ out)
{
  const int b = blockIdx.x;
  const int l = threadIdx.x;
  float sigv[6];
#pragma unroll
  for (int ii = 0; ii < 6; ++ii) {
    int jj = l + ii * 64;
    sigv[ii] = (jj < SIGDIMc)
        ? (g_psig[(size_t)(2 * b) * SIGDIMc + jj] +
           g_psig[(size_t)(2 * b + 1) * SIGDIMc + jj]) * (1.0f / 64.0f)
        : 0.f;
  }
  float lgv[NCLSc];
#pragma unroll 1
  for (int c = 0; c < NCLSc; ++c) {
    float s = 0.f;
#pragma unroll
    for (int ii = 0; ii < 6; ++ii) {
      int jj = l + ii * 64;
      if (jj < SIGDIMc) s = fmaf(sigv[ii], Wf[c * SIGDIMc + jj], s);
    }
#pragma unroll
    for (int off = 1; off < 64; off <<= 1) s += __shfl_xor(s, off);
    lgv[c] = s + bf[c];
  }
  if (l < NCLSc) {
    float mx = lgv[0];
#pragma unroll
    for (int i2 = 1; i2 < NCLSc; ++i2) mx = fmaxf(mx, lgv[i2]);
    float se = 0.f;
#pragma unroll
    for (int i2 = 0; i2 < NCLSc; ++i2) se += expf(lgv[i2] - mx);
    out[b * NCLSc + l] = lgv[l] - mx - logf(se);
  }
}

extern "C" void kernel_launch(void* const* d_in, const int* in_sizes, int n_in,
                              void* d_out, int out_size, void* d_ws, size_t ws_size,
                              hipStream_t stream) {
  (void)in_sizes; (void)n_in; (void)out_size; (void)d_ws; (void)ws_size;
  const float* x   = (const float*)d_in[0];
  const float* Wm  = (const float*)d_in[1];
  const float* bm  = (const float*)d_in[2];
  const float* Wc  = (const float*)d_in[3];
  const float* bcv = (const float*)d_in[4];
  const float* Wf  = (const float*)d_in[5];
  const float* bf  = (const float*)d_in[6];
  const float* eps = (const float*)d_in[7];
  // d_in[8]/d_in[9] (x_idx/y_idx) are compile-time deterministic; hard-coded.
  float* out = (float*)d_out;

  gemm_mc<<<dim3(48, 8), 256, 0, stream>>>(x, Wm, bm, Wc, bcv);
  path_sig<<<dim3(512), 1024, 0, stream>>>(x, eps);
  finish<<<dim3(256), 64, 0, stream>>>(Wf, bf, out);
}